// Round 2
// baseline (144.730 us; speedup 1.0000x reference)
//
#include <hip/hip_runtime.h>
#include <hip/hip_bf16.h>

// Problem constants (from reference)
#define BATCH      8
#define S_BYTES    8192
#define NUM_EMB    384
#define BYTE_DIM   128
#define EMB_DIM    1024
#define NUM_TOKENS 2048
#define SCALE_F    11.313708498984761f   // sqrt(128)

#define M_TOTAL (BATCH * NUM_TOKENS)     // 16384 rows into the GEMM

typedef __bf16 bf16x8 __attribute__((ext_vector_type(8)));
typedef float  floatx4 __attribute__((ext_vector_type(4)));

// ---------------------------------------------------------------------------
// Kernel 0: convert out_proj_w fp32 -> bf16.  131072 elements, 4 per thread.
// ---------------------------------------------------------------------------
__global__ __launch_bounds__(256) void convert_w_kernel(
    const float* __restrict__ w,          // [EMB_DIM, BYTE_DIM] fp32
    __hip_bfloat16* __restrict__ wb)      // [EMB_DIM, BYTE_DIM] bf16
{
    const int i = (blockIdx.x * 256 + threadIdx.x) * 4;  // 128 blocks covers 131072
    const float4 v = *(const float4*)(w + i);
    wb[i + 0] = __float2bfloat16(v.x);
    wb[i + 1] = __float2bfloat16(v.y);
    wb[i + 2] = __float2bfloat16(v.z);
    wb[i + 3] = __float2bfloat16(v.w);
}

// ---------------------------------------------------------------------------
// Kernel 1: segment-mean pooling.
// One block per (b, token): binary search the sorted byte_groups row for the
// segment [lo, hi), accumulate gathered fp32 embedding rows, write bf16.
// 128 threads = one per dim; emb table (192 KB fp32) is L2-resident.
// ---------------------------------------------------------------------------
__global__ __launch_bounds__(128) void pool_kernel(
    const int* __restrict__ x,                 // [B, S_BYTES]
    const int* __restrict__ bg,                // [B, S_BYTES] sorted per row
    const float* __restrict__ emb,             // [NUM_EMB, BYTE_DIM] fp32
    __hip_bfloat16* __restrict__ grouped)      // [B*NUM_TOKENS, BYTE_DIM] bf16
{
    const int blk = blockIdx.x;                // b * NUM_TOKENS + t
    const int b   = blk >> 11;                 // / NUM_TOKENS
    const int t   = blk & (NUM_TOKENS - 1);

    const int* __restrict__ row = bg + b * S_BYTES;

    // lower_bound(t)
    int lo = 0, hi = S_BYTES;
    while (lo < hi) { int m = (lo + hi) >> 1; if (row[m] < t) lo = m + 1; else hi = m; }
    // lower_bound(t+1)
    hi = S_BYTES;
    while (lo < hi) { int m = (lo + hi) >> 1; if (row[m] < t + 1) lo = m + 1; else hi = m; }
    // after first loop, lo==seg_start; re-derive:
    // (second loop reused lo as running lower bound starting at seg_start)
    // seg_start recomputed below via a saved copy
    // -- implemented with explicit saves:
    // (see seg_start/seg_end below)
    const int seg_end = lo;

    // redo first search to recover seg_start cheaply (rows are L1-hot now)
    int lo2 = 0, hi2 = seg_end;
    while (lo2 < hi2) { int m = (lo2 + hi2) >> 1; if (row[m] < t) lo2 = m + 1; else hi2 = m; }
    const int seg_start = lo2;

    const int cnt = seg_end - seg_start;
    const int d = threadIdx.x;

    float sum = 0.0f;
    const int* __restrict__ xrow = x + b * S_BYTES;
    for (int i = seg_start; i < seg_end; ++i) {
        const int e = xrow[i];                      // broadcast across lanes
        sum += emb[e * BYTE_DIM + d];               // coalesced 512B row
    }
    const float inv = SCALE_F / (float)(cnt > 1 ? cnt : 1);
    grouped[blk * BYTE_DIM + d] = __float2bfloat16(sum * inv);
}

// ---------------------------------------------------------------------------
// Kernel 2: GEMM  out[m, e] = sum_k grouped[m, k] * Wb[e, k]   (fp32 out)
// Both operands K-contiguous (B^T layout). mfma_f32_16x16x32_bf16.
// One wave computes a 32x32 output tile: 2x2 acc tiles, K=128 (4 k-steps).
// A-frag: A[m = lane&15][k = (lane>>4)*8 + j]  (m89-verified layout)
// C/D:    col(n) = lane&15, row(m) = (lane>>4)*4 + reg
// ---------------------------------------------------------------------------
__global__ __launch_bounds__(256) void gemm_kernel(
    const __hip_bfloat16* __restrict__ A,   // [M_TOTAL, 128] bf16
    const __hip_bfloat16* __restrict__ W,   // [EMB_DIM, 128] bf16
    float* __restrict__ out)                // [M_TOTAL, EMB_DIM] fp32
{
    const int wave = (blockIdx.x * 256 + threadIdx.x) >> 6;  // global wave id
    const int lane = threadIdx.x & 63;
    // 32x32 tiles: M/32 = 512, N/32 = 32
    const int m32 = wave >> 5;          // 0..511
    const int n32 = wave & 31;          // 0..31
    const int r    = lane & 15;
    const int quad = lane >> 4;

    const bf16x8* __restrict__ A0 = (const bf16x8*)(A + (m32 * 32 + r     ) * BYTE_DIM + quad * 8);
    const bf16x8* __restrict__ A1 = (const bf16x8*)(A + (m32 * 32 + r + 16) * BYTE_DIM + quad * 8);
    const bf16x8* __restrict__ B0 = (const bf16x8*)(W + (n32 * 32 + r     ) * BYTE_DIM + quad * 8);
    const bf16x8* __restrict__ B1 = (const bf16x8*)(W + (n32 * 32 + r + 16) * BYTE_DIM + quad * 8);

    floatx4 acc00 = {0.f, 0.f, 0.f, 0.f};
    floatx4 acc01 = {0.f, 0.f, 0.f, 0.f};
    floatx4 acc10 = {0.f, 0.f, 0.f, 0.f};
    floatx4 acc11 = {0.f, 0.f, 0.f, 0.f};

    #pragma unroll
    for (int kk = 0; kk < 4; ++kk) {
        const bf16x8 a0 = A0[kk * 4];
        const bf16x8 a1 = A1[kk * 4];
        const bf16x8 b0 = B0[kk * 4];
        const bf16x8 b1 = B1[kk * 4];
        acc00 = __builtin_amdgcn_mfma_f32_16x16x32_bf16(a0, b0, acc00, 0, 0, 0);
        acc01 = __builtin_amdgcn_mfma_f32_16x16x32_bf16(a0, b1, acc01, 0, 0, 0);
        acc10 = __builtin_amdgcn_mfma_f32_16x16x32_bf16(a1, b0, acc10, 0, 0, 0);
        acc11 = __builtin_amdgcn_mfma_f32_16x16x32_bf16(a1, b1, acc11, 0, 0, 0);
    }

    const int mbase = m32 * 32 + quad * 4;
    const int nbase = n32 * 32 + r;
    #pragma unroll
    for (int reg = 0; reg < 4; ++reg) {
        const int r0 = mbase + reg;
        out[(r0     ) * EMB_DIM + nbase     ] = acc00[reg];
        out[(r0     ) * EMB_DIM + nbase + 16] = acc01[reg];
        out[(r0 + 16) * EMB_DIM + nbase     ] = acc10[reg];
        out[(r0 + 16) * EMB_DIM + nbase + 16] = acc11[reg];
    }
}

extern "C" void kernel_launch(void* const* d_in, const int* in_sizes, int n_in,
                              void* d_out, int out_size, void* d_ws, size_t ws_size,
                              hipStream_t stream) {
    const int*   x   = (const int*)d_in[0];     // [8, 8192] int32
    const int*   bg  = (const int*)d_in[1];     // [8, 8192] int32 (sorted rows)
    const float* emb = (const float*)d_in[2];   // [384, 128] fp32
    const float* w   = (const float*)d_in[3];   // [1024, 128] fp32
    float*       out = (float*)d_out;           // [16384, 1024] fp32

    // workspace layout: grouped bf16 [16384,128] = 4 MB, then Wb bf16 = 256 KB
    __hip_bfloat16* grouped = (__hip_bfloat16*)d_ws;
    __hip_bfloat16* wb      = (__hip_bfloat16*)((char*)d_ws + (size_t)M_TOTAL * BYTE_DIM * 2);

    convert_w_kernel<<<(EMB_DIM * BYTE_DIM) / (256 * 4), 256, 0, stream>>>(w, wb);
    pool_kernel<<<BATCH * NUM_TOKENS, 128, 0, stream>>>(x, bg, emb, grouped);
    // 16384 waves (512 x 32 tiles of 32x32), 4 waves per 256-thread block
    gemm_kernel<<<(M_TOTAL / 32) * (EMB_DIM / 32) / 4, 256, 0, stream>>>(grouped, wb, out);
}

// Round 3
// 119.243 us; speedup vs baseline: 1.2137x; 1.2137x over previous
//
#include <hip/hip_runtime.h>
#include <hip/hip_bf16.h>

// Problem constants (from reference)
#define BATCH      8
#define S_BYTES    8192
#define NUM_EMB    384
#define BYTE_DIM   128
#define EMB_DIM    1024
#define NUM_TOKENS 2048
#define SCALE_F    11.313708498984761f   // sqrt(128)

#define M_TOTAL (BATCH * NUM_TOKENS)     // 16384 rows into the GEMM
#define SEG_STRIDE 2064                  // 2049 entries padded

typedef __bf16 bf16x8 __attribute__((ext_vector_type(8)));
typedef float  floatx4 __attribute__((ext_vector_type(4)));

// ---------------------------------------------------------------------------
// Kernel A (fused): blockIdx < 256  -> segment-boundary precompute
//                   blockIdx >= 256 -> out_proj_w fp32 -> bf16 convert
// Boundary: bg rows are sorted; thread (b,i) writes seg[b][t] = i for all
// t in (bg[i-1], bg[i]]  (thread i==S-1 also writes the tail up to t=2048).
// Every seg[b][0..2048] entry is written exactly once.
// ---------------------------------------------------------------------------
__global__ __launch_bounds__(256) void prep_kernel(
    const int* __restrict__ bg,           // [B, S_BYTES] sorted per row
    int* __restrict__ seg,                // [B, SEG_STRIDE]
    const float* __restrict__ w,          // [EMB_DIM, BYTE_DIM] fp32
    __hip_bfloat16* __restrict__ wb)      // [EMB_DIM, BYTE_DIM] bf16
{
    if (blockIdx.x < 256) {
        const int gid = blockIdx.x * 256 + threadIdx.x;   // 0..65535
        const int b = gid >> 13;
        const int i = gid & (S_BYTES - 1);
        const int g  = bg[gid];
        const int gp = (i == 0) ? -1 : bg[gid - 1];
        int* __restrict__ srow = seg + b * SEG_STRIDE;
        for (int t = gp + 1; t <= g; ++t) srow[t] = i;
        if (i == S_BYTES - 1) {
            for (int t = g + 1; t <= NUM_TOKENS; ++t) srow[t] = S_BYTES;
        }
    } else {
        const int i = ((blockIdx.x - 256) * 256 + threadIdx.x) * 4;  // 128 blocks
        const float4 v = *(const float4*)(w + i);
        wb[i + 0] = __float2bfloat16(v.x);
        wb[i + 1] = __float2bfloat16(v.y);
        wb[i + 2] = __float2bfloat16(v.z);
        wb[i + 3] = __float2bfloat16(v.w);
    }
}

// ---------------------------------------------------------------------------
// Kernel B: segment-mean pooling, O(1) bounds lookup.
// One block per (b, token), 128 threads = one per dim. Stage the segment's
// x indices through LDS (one parallel global round), then accumulate the
// gathered emb rows (independent loads, unrolled 4-deep).
// ---------------------------------------------------------------------------
__global__ __launch_bounds__(128) void pool_kernel(
    const int* __restrict__ x,                 // [B, S_BYTES]
    const int* __restrict__ seg,               // [B, SEG_STRIDE]
    const float* __restrict__ emb,             // [NUM_EMB, BYTE_DIM] fp32
    __hip_bfloat16* __restrict__ grouped)      // [B*NUM_TOKENS, BYTE_DIM] bf16
{
    const int blk = blockIdx.x;                // b * NUM_TOKENS + t
    const int b   = blk >> 11;
    const int t   = blk & (NUM_TOKENS - 1);

    const int s   = seg[b * SEG_STRIDE + t];
    const int e   = seg[b * SEG_STRIDE + t + 1];
    const int cnt = e - s;

    __shared__ int sx[256];
    const int* __restrict__ xrow = x + b * S_BYTES;
    const int d = threadIdx.x;

    float sum = 0.0f;
    for (int base = 0; base < cnt; base += 256) {
        const int chunk = min(cnt - base, 256);
        __syncthreads();
        for (int i = threadIdx.x; i < chunk; i += 128) sx[i] = xrow[s + base + i];
        __syncthreads();
        #pragma unroll 4
        for (int i = 0; i < chunk; ++i) sum += emb[sx[i] * BYTE_DIM + d];
    }
    const float inv = SCALE_F / (float)(cnt > 1 ? cnt : 1);
    grouped[blk * BYTE_DIM + d] = __float2bfloat16(sum * inv);
}

// ---------------------------------------------------------------------------
// Kernel C: GEMM  out[m, e] = sum_k grouped[m, k] * Wb[e, k]   (fp32 out)
// Both operands K-contiguous. mfma_f32_16x16x32_bf16, one wave = 32x32 tile.
// A-frag: A[m = lane&15][k = (lane>>4)*8 + j]  (m89-verified layout)
// C/D:    col(n) = lane&15, row(m) = (lane>>4)*4 + reg
// ---------------------------------------------------------------------------
__global__ __launch_bounds__(256) void gemm_kernel(
    const __hip_bfloat16* __restrict__ A,   // [M_TOTAL, 128] bf16
    const __hip_bfloat16* __restrict__ W,   // [EMB_DIM, 128] bf16
    float* __restrict__ out)                // [M_TOTAL, EMB_DIM] fp32
{
    const int wave = (blockIdx.x * 256 + threadIdx.x) >> 6;
    const int lane = threadIdx.x & 63;
    const int m32 = wave >> 5;          // 0..511
    const int n32 = wave & 31;          // 0..31
    const int r    = lane & 15;
    const int quad = lane >> 4;

    const bf16x8* __restrict__ A0 = (const bf16x8*)(A + (m32 * 32 + r     ) * BYTE_DIM + quad * 8);
    const bf16x8* __restrict__ A1 = (const bf16x8*)(A + (m32 * 32 + r + 16) * BYTE_DIM + quad * 8);
    const bf16x8* __restrict__ B0 = (const bf16x8*)(W + (n32 * 32 + r     ) * BYTE_DIM + quad * 8);
    const bf16x8* __restrict__ B1 = (const bf16x8*)(W + (n32 * 32 + r + 16) * BYTE_DIM + quad * 8);

    floatx4 acc00 = {0.f, 0.f, 0.f, 0.f};
    floatx4 acc01 = {0.f, 0.f, 0.f, 0.f};
    floatx4 acc10 = {0.f, 0.f, 0.f, 0.f};
    floatx4 acc11 = {0.f, 0.f, 0.f, 0.f};

    #pragma unroll
    for (int kk = 0; kk < 4; ++kk) {
        const bf16x8 a0 = A0[kk * 4];
        const bf16x8 a1 = A1[kk * 4];
        const bf16x8 b0 = B0[kk * 4];
        const bf16x8 b1 = B1[kk * 4];
        acc00 = __builtin_amdgcn_mfma_f32_16x16x32_bf16(a0, b0, acc00, 0, 0, 0);
        acc01 = __builtin_amdgcn_mfma_f32_16x16x32_bf16(a0, b1, acc01, 0, 0, 0);
        acc10 = __builtin_amdgcn_mfma_f32_16x16x32_bf16(a1, b0, acc10, 0, 0, 0);
        acc11 = __builtin_amdgcn_mfma_f32_16x16x32_bf16(a1, b1, acc11, 0, 0, 0);
    }

    const int mbase = m32 * 32 + quad * 4;
    const int nbase = n32 * 32 + r;
    #pragma unroll
    for (int reg = 0; reg < 4; ++reg) {
        const int r0 = mbase + reg;
        out[(r0     ) * EMB_DIM + nbase     ] = acc00[reg];
        out[(r0     ) * EMB_DIM + nbase + 16] = acc01[reg];
        out[(r0 + 16) * EMB_DIM + nbase     ] = acc10[reg];
        out[(r0 + 16) * EMB_DIM + nbase + 16] = acc11[reg];
    }
}

extern "C" void kernel_launch(void* const* d_in, const int* in_sizes, int n_in,
                              void* d_out, int out_size, void* d_ws, size_t ws_size,
                              hipStream_t stream) {
    const int*   x   = (const int*)d_in[0];     // [8, 8192] int32
    const int*   bg  = (const int*)d_in[1];     // [8, 8192] int32 (sorted rows)
    const float* emb = (const float*)d_in[2];   // [384, 128] fp32
    const float* w   = (const float*)d_in[3];   // [1024, 128] fp32
    float*       out = (float*)d_out;           // [16384, 1024] fp32

    // ws layout: grouped bf16 [16384,128] (4 MB) | wb bf16 (256 KB) | seg int [8][2064]
    __hip_bfloat16* grouped = (__hip_bfloat16*)d_ws;
    __hip_bfloat16* wb      = (__hip_bfloat16*)((char*)d_ws + (size_t)M_TOTAL * BYTE_DIM * 2);
    int*            seg     = (int*)((char*)d_ws + (size_t)M_TOTAL * BYTE_DIM * 2
                                                 + (size_t)EMB_DIM * BYTE_DIM * 2);

    // 256 boundary blocks + 128 convert blocks
    prep_kernel<<<256 + (EMB_DIM * BYTE_DIM) / (256 * 4), 256, 0, stream>>>(bg, seg, w, wb);
    pool_kernel<<<BATCH * NUM_TOKENS, 128, 0, stream>>>(x, seg, emb, grouped);
    gemm_kernel<<<(M_TOTAL / 32) * (EMB_DIM / 32) / 4, 256, 0, stream>>>(grouped, wb, out);
}

// Round 4
// 97.728 us; speedup vs baseline: 1.4809x; 1.2202x over previous
//
#include <hip/hip_runtime.h>
#include <hip/hip_bf16.h>

// Problem constants (from reference)
#define BATCH      8
#define S_BYTES    8192
#define NUM_EMB    384
#define BYTE_DIM   128
#define EMB_DIM    1024
#define NUM_TOKENS 2048
#define SCALE_F    11.313708498984761f   // sqrt(128)

#define M_TOTAL (BATCH * NUM_TOKENS)     // 16384 rows into the GEMM
#define SEG_STRIDE 2064                  // 2049 entries padded

typedef __bf16 bf16x8 __attribute__((ext_vector_type(8)));
typedef float  floatx4 __attribute__((ext_vector_type(4)));

// ---------------------------------------------------------------------------
// Kernel A (fused): blockIdx < 256  -> segment-boundary precompute
//                   blockIdx >= 256 -> out_proj_w fp32 -> bf16 convert
// ---------------------------------------------------------------------------
__global__ __launch_bounds__(256) void prep_kernel(
    const int* __restrict__ bg,           // [B, S_BYTES] sorted per row
    int* __restrict__ seg,                // [B, SEG_STRIDE]
    const float* __restrict__ w,          // [EMB_DIM, BYTE_DIM] fp32
    __hip_bfloat16* __restrict__ wb)      // [EMB_DIM, BYTE_DIM] bf16
{
    if (blockIdx.x < 256) {
        const int gid = blockIdx.x * 256 + threadIdx.x;   // 0..65535
        const int b = gid >> 13;
        const int i = gid & (S_BYTES - 1);
        const int g  = bg[gid];
        const int gp = (i == 0) ? -1 : bg[gid - 1];
        int* __restrict__ srow = seg + b * SEG_STRIDE;
        for (int t = gp + 1; t <= g; ++t) srow[t] = i;
        if (i == S_BYTES - 1) {
            for (int t = g + 1; t <= NUM_TOKENS; ++t) srow[t] = S_BYTES;
        }
    } else {
        const int i = ((blockIdx.x - 256) * 256 + threadIdx.x) * 4;  // 128 blocks
        const float4 v = *(const float4*)(w + i);
        wb[i + 0] = __float2bfloat16(v.x);
        wb[i + 1] = __float2bfloat16(v.y);
        wb[i + 2] = __float2bfloat16(v.z);
        wb[i + 3] = __float2bfloat16(v.w);
    }
}

// ---------------------------------------------------------------------------
// Kernel B: segment-mean pooling, O(1) bounds lookup. (unchanged from R3)
// ---------------------------------------------------------------------------
__global__ __launch_bounds__(128) void pool_kernel(
    const int* __restrict__ x,                 // [B, S_BYTES]
    const int* __restrict__ seg,               // [B, SEG_STRIDE]
    const float* __restrict__ emb,             // [NUM_EMB, BYTE_DIM] fp32
    __hip_bfloat16* __restrict__ grouped)      // [B*NUM_TOKENS, BYTE_DIM] bf16
{
    const int blk = blockIdx.x;                // b * NUM_TOKENS + t
    const int b   = blk >> 11;
    const int t   = blk & (NUM_TOKENS - 1);

    const int s   = seg[b * SEG_STRIDE + t];
    const int e   = seg[b * SEG_STRIDE + t + 1];
    const int cnt = e - s;

    __shared__ int sx[256];
    const int* __restrict__ xrow = x + b * S_BYTES;
    const int d = threadIdx.x;

    float sum = 0.0f;
    for (int base = 0; base < cnt; base += 256) {
        const int chunk = min(cnt - base, 256);
        __syncthreads();
        for (int i = threadIdx.x; i < chunk; i += 128) sx[i] = xrow[s + base + i];
        __syncthreads();
        #pragma unroll 4
        for (int i = 0; i < chunk; ++i) sum += emb[sx[i] * BYTE_DIM + d];
    }
    const float inv = SCALE_F / (float)(cnt > 1 ? cnt : 1);
    grouped[blk * BYTE_DIM + d] = __float2bfloat16(sum * inv);
}

// ---------------------------------------------------------------------------
// Kernel C: GEMM, m97-style LDS-staged 128x128 block, K=128 (single stage).
//   out[m, e] = sum_k grouped[m, k] * Wb[e, k]   (fp32 out)
// Block = 256 threads = 4 waves in a 2x2 grid; each wave computes 64x64
// (4x4 subtiles of 16x16, mfma_f32_16x16x32_bf16, 64 MFMA / 32 ds_read_b128).
// A-frag: A[m = lane&15][k = (lane>>4)*8 + j]; C/D: col=lane&15, row=quad*4+reg.
// Staging: register copy global->LDS, 16 B per thread x 8 iters per operand.
// ---------------------------------------------------------------------------
__global__ __launch_bounds__(256) void gemm_kernel(
    const __hip_bfloat16* __restrict__ A,   // [M_TOTAL, 128] bf16
    const __hip_bfloat16* __restrict__ W,   // [EMB_DIM, 128] bf16
    float* __restrict__ out)                // [M_TOTAL, EMB_DIM] fp32
{
    __shared__ __hip_bfloat16 sA[128 * 128];   // 32 KB, [m][k]
    __shared__ __hip_bfloat16 sB[128 * 128];   // 32 KB, [n][k]

    // mb fast -> consecutive blocks (round-robin over XCDs) take different mb,
    // so each XCD touches only ~1/8 of A per nb-pass (L2-resident working set).
    const int mb = blockIdx.x & 127;           // 128 M-blocks
    const int nb = blockIdx.x >> 7;            // 8 N-blocks
    const int m0 = mb * 128;
    const int n0 = nb * 128;
    const int tid = threadIdx.x;

    // ---- stage A-tile and B-tile (each 16384 elems = 2048 x 16B chunks) ----
    {
        const bf16x8* __restrict__ gA = (const bf16x8*)(A + (size_t)m0 * BYTE_DIM);
        const bf16x8* __restrict__ gB = (const bf16x8*)(W + (size_t)n0 * BYTE_DIM);
        bf16x8* __restrict__ lA = (bf16x8*)sA;
        bf16x8* __restrict__ lB = (bf16x8*)sB;
        #pragma unroll
        for (int i = 0; i < 8; ++i) {
            lA[tid + i * 256] = gA[tid + i * 256];
            lB[tid + i * 256] = gB[tid + i * 256];
        }
    }
    __syncthreads();

    const int wave = tid >> 6;
    const int lane = tid & 63;
    const int wm = wave >> 1;        // 0..1
    const int wn = wave & 1;         // 0..1
    const int r    = lane & 15;
    const int quad = lane >> 4;

    floatx4 acc[4][4] = {};

    #pragma unroll
    for (int kk = 0; kk < 4; ++kk) {
        bf16x8 af[4], bfr[4];
        #pragma unroll
        for (int i = 0; i < 4; ++i)
            af[i] = *(const bf16x8*)(sA + (wm * 64 + i * 16 + r) * BYTE_DIM + kk * 32 + quad * 8);
        #pragma unroll
        for (int j = 0; j < 4; ++j)
            bfr[j] = *(const bf16x8*)(sB + (wn * 64 + j * 16 + r) * BYTE_DIM + kk * 32 + quad * 8);
        #pragma unroll
        for (int i = 0; i < 4; ++i)
            #pragma unroll
            for (int j = 0; j < 4; ++j)
                acc[i][j] = __builtin_amdgcn_mfma_f32_16x16x32_bf16(af[i], bfr[j], acc[i][j], 0, 0, 0);
    }

    // ---- epilogue: fp32 scattered stores (L2 merges the 64B half-lines) ----
    #pragma unroll
    for (int i = 0; i < 4; ++i) {
        const int mrow = m0 + wm * 64 + i * 16 + quad * 4;
        #pragma unroll
        for (int j = 0; j < 4; ++j) {
            const int ncol = n0 + wn * 64 + j * 16 + r;
            float* __restrict__ p = out + (size_t)mrow * EMB_DIM + ncol;
            #pragma unroll
            for (int reg = 0; reg < 4; ++reg)
                p[(size_t)reg * EMB_DIM] = acc[i][j][reg];
        }
    }
}

extern "C" void kernel_launch(void* const* d_in, const int* in_sizes, int n_in,
                              void* d_out, int out_size, void* d_ws, size_t ws_size,
                              hipStream_t stream) {
    const int*   x   = (const int*)d_in[0];     // [8, 8192] int32
    const int*   bg  = (const int*)d_in[1];     // [8, 8192] int32 (sorted rows)
    const float* emb = (const float*)d_in[2];   // [384, 128] fp32
    const float* w   = (const float*)d_in[3];   // [1024, 128] fp32
    float*       out = (float*)d_out;           // [16384, 1024] fp32

    // ws layout: grouped bf16 [16384,128] (4 MB) | wb bf16 (256 KB) | seg int [8][2064]
    __hip_bfloat16* grouped = (__hip_bfloat16*)d_ws;
    __hip_bfloat16* wb      = (__hip_bfloat16*)((char*)d_ws + (size_t)M_TOTAL * BYTE_DIM * 2);
    int*            seg     = (int*)((char*)d_ws + (size_t)M_TOTAL * BYTE_DIM * 2
                                                 + (size_t)EMB_DIM * BYTE_DIM * 2);

    prep_kernel<<<256 + (EMB_DIM * BYTE_DIM) / (256 * 4), 256, 0, stream>>>(bg, seg, w, wb);
    pool_kernel<<<BATCH * NUM_TOKENS, 128, 0, stream>>>(x, seg, emb, grouped);
    // 128 M-blocks x 8 N-blocks of 128x128
    gemm_kernel<<<(M_TOTAL / 128) * (EMB_DIM / 128), 256, 0, stream>>>(grouped, wb, out);
}